// Round 18
// baseline (289.957 us; speedup 1.0000x reference)
//
#include <hip/hip_runtime.h>
#include <hip/hip_bf16.h>

#define NASP 5
#define H1 10
#define SEQ 500
#define EMB 300
#define THREADS 512
#define NKS 10                        // ceil(300/32) k-steps
#define BF_ELEMS (NKS * 4 * 64 * 8)   // 20480 bf16 = 40 KB
#define SCSTR 18                      // score buffer row stride (floats)
#define ATTN_STR 520                  // attn LDS row stride (shorts)
#define RED_OFF 9260                  // red[] offset (floats)
#define PART_OFF 1536                 // pooling partial buffer offset (floats), [32][16][6]

// streaming LDS geometry (shorts): row stride 304 (608 B), buf = 32*304+32 pad = 9760,
// buf0 @0, buf1 @9760, B-frags @19520 (byte 39040). Total 80000 B -> 2 blocks/CU.
#define RSTR 304
#define BUFS 9760
#define BOFF 19520

typedef float  f32x4  __attribute__((ext_vector_type(4)));
typedef __bf16 bf16x8 __attribute__((ext_vector_type(8)));
typedef short  s16x8  __attribute__((ext_vector_type(8)));
union frag_cast { s16x8 s; bf16x8 b; };

__device__ __host__ inline short f2bf_rne(float x) {
    unsigned u = __builtin_bit_cast(unsigned, x);
    u = u + 0x7FFF + ((u >> 16) & 1);
    return (short)(u >> 16);
}

// ---- prep: B-fragments Bf[ks][nt][lane][8] (bf16) ----
// nt<3 : proj cols 0..47; nt==3: q<2 -> cols 48,49 ; q>=2 -> F col c=q-2 (c=slot*5+a)
__global__ void build_bfrag(const float* __restrict__ Wg, const float* __restrict__ embG,
                            short* __restrict__ Bf) {
    int i = blockIdx.x * blockDim.x + threadIdx.x;
    if (i >= BF_ELEMS) return;
    int j    = i & 7;
    int lane = (i >> 3) & 63;
    int nt   = (i >> 9) & 3;
    int ks   = i >> 11;
    int k    = ks * 32 + (lane >> 4) * 8 + j;
    int q    = lane & 15;
    float v = 0.f;
    if (k < EMB) {
        if (nt < 3) {
            int col = nt * 16 + q;
            int a = col / 10, h = col - 10 * a;
            v = Wg[a * 3000 + k * 10 + h];
        } else if (q < 2) {
            v = Wg[4 * 3000 + k * 10 + 8 + q];
        } else {
            int c = q - 2;
            int slot = c / 5, a = c - 5 * slot;
            float sacc = 0.f;
            #pragma unroll
            for (int h = 0; h < 10; ++h)
                sacc += Wg[a * 3000 + k * 10 + h] * embG[a * 30 + slot * 10 + h];
            v = sacc;
        }
    }
    Bf[i] = f2bf_rne(v);
}

// consume one 32-row staged chunk into acc[I0]/acc[I1] — MACRO with literal indices
// (function-with-array-ref defeated SROA in r16 -> acc demoted to scratch; rule #20)
#define CONSUME(I0, I1)                                                                   \
    _Pragma("unroll")                                                                     \
    for (int ks = 0; ks < NKS; ++ks) {                                                    \
        frag_cast bfr0, bfr1, bfr2, bfr3;                                                 \
        bfr0.s = *reinterpret_cast<const s16x8*>(SBs + BOFF + ((ks * 4 + 0) * 64 + lane) * 8); \
        bfr1.s = *reinterpret_cast<const s16x8*>(SBs + BOFF + ((ks * 4 + 1) * 64 + lane) * 8); \
        bfr2.s = *reinterpret_cast<const s16x8*>(SBs + BOFF + ((ks * 4 + 2) * 64 + lane) * 8); \
        bfr3.s = *reinterpret_cast<const s16x8*>(SBs + BOFF + ((ks * 4 + 3) * 64 + lane) * 8); \
        frag_cast a0, a1;                                                                 \
        a0.s = *reinterpret_cast<const s16x8*>(SBs + rbase + q * RSTR + ks * 32 + kg * 8);        \
        a1.s = *reinterpret_cast<const s16x8*>(SBs + rbase + (16 + q) * RSTR + ks * 32 + kg * 8); \
        acc[I0][0] = __builtin_amdgcn_mfma_f32_16x16x32_bf16(a0.b, bfr0.b, acc[I0][0], 0, 0, 0);  \
        acc[I0][1] = __builtin_amdgcn_mfma_f32_16x16x32_bf16(a0.b, bfr1.b, acc[I0][1], 0, 0, 0);  \
        acc[I0][2] = __builtin_amdgcn_mfma_f32_16x16x32_bf16(a0.b, bfr2.b, acc[I0][2], 0, 0, 0);  \
        acc[I0][3] = __builtin_amdgcn_mfma_f32_16x16x32_bf16(a0.b, bfr3.b, acc[I0][3], 0, 0, 0);  \
        acc[I1][0] = __builtin_amdgcn_mfma_f32_16x16x32_bf16(a1.b, bfr0.b, acc[I1][0], 0, 0, 0);  \
        acc[I1][1] = __builtin_amdgcn_mfma_f32_16x16x32_bf16(a1.b, bfr1.b, acc[I1][1], 0, 0, 0);  \
        acc[I1][2] = __builtin_amdgcn_mfma_f32_16x16x32_bf16(a1.b, bfr2.b, acc[I1][2], 0, 0, 0);  \
        acc[I1][3] = __builtin_amdgcn_mfma_f32_16x16x32_bf16(a1.b, bfr3.b, acc[I1][3], 0, 0, 0);  \
    }

#define LOAD_SLOT(vv, IT) { int fq = tid + (IT)*512; int rl = fq / 75; int c4 = fq - rl * 75; \
    int gr = cc * 32 + rl; gr = gr > 499 ? 499 : gr;                                          \
    vv = *reinterpret_cast<const float4*>(docB + gr * 300 + c4 * 4); }
#define WRITE_SLOT(vv, IT) { int fq = tid + (IT)*512; int rl = fq / 75; int c4 = fq - rl * 75; \
    short4 w; w.x = f2bf_rne(vv.x); w.y = f2bf_rne(vv.y); w.z = f2bf_rne(vv.z);               \
    w.w = f2bf_rne(vv.w);                                                                     \
    *reinterpret_cast<short4*>(SBs + wbase + rl * RSTR + c4 * 4) = w; }

__global__ __launch_bounds__(THREADS, 4)
void arl_mfma(const float* __restrict__ doc,
              const short* __restrict__ Bf,
              const float* __restrict__ embG,
              float* __restrict__ out,
              int B) {
    __shared__ float SB[20000];          // 80 KB: 2 chunk bufs + B-frags / epilogue overlay

    const int tid  = threadIdx.x;
    const int b    = blockIdx.x;
    const int lane = tid & 63;
    const int wave = tid >> 6;
    const int q    = lane & 15;
    const int kg   = lane >> 4;
    const int s    = tid;
    const bool active = (s < SEQ);

    const float* docB = doc + (size_t)b * (SEQ * EMB);
    short* SBs = reinterpret_cast<short*>(SB);

    // ---- init: zero per-row slack cols 300..303 (both bufs) and 64B tail pads.
    // NaN hygiene: ks=9 kg>=1 fragment reads overrun into these; must be finite.
    if (tid < 64) {
        int bufI = tid >> 5, row = tid & 31;
        *reinterpret_cast<short4*>(SBs + bufI * BUFS + row * RSTR + 300) = (short4){0, 0, 0, 0};
    } else if (tid < 80) {
        SB[4864 + (tid - 64)] = 0.f;                       // buf0 tail pad (shorts 9728..9759)
    } else if (tid < 96) {
        SB[9744 + (tid - 80)] = 0.f;                       // buf1 tail pad (shorts 19488..19519)
    }

    // ---- stage B-fragments into LDS: 2560 float4 at float4-index 2440 (byte 39040) ----
    {
        const float4* bsrc = reinterpret_cast<const float4*>(Bf);
        float4* bdst = reinterpret_cast<float4*>(SB) + 2440;
        #pragma unroll
        for (int i = 0; i < 5; ++i)
            bdst[tid + i * THREADS] = bsrc[tid + i * THREADS];
    }

    f32x4 acc[4][4];
    #pragma unroll
    for (int i = 0; i < 4; ++i)
        #pragma unroll
        for (int nt = 0; nt < 4; ++nt)
            acc[i][nt] = (f32x4){0.f, 0.f, 0.f, 0.f};

    // ---- prologue: stage chunk 0 into buf0 ----
    {
        const int cc = 0, wbase = 0;
        float4 v0, v1, v2, v3, v4;
        LOAD_SLOT(v0, 0) LOAD_SLOT(v1, 1) LOAD_SLOT(v2, 2) LOAD_SLOT(v3, 3)
        if (tid < 352) { LOAD_SLOT(v4, 4) }
        WRITE_SLOT(v0, 0) WRITE_SLOT(v1, 1) WRITE_SLOT(v2, 2) WRITE_SLOT(v3, 3)
        if (tid < 352) { WRITE_SLOT(v4, 4) }
    }
    __syncthreads();

    // ---------------- phase 1: 16 windows, double-buffered contiguous streaming ------
    // Window c: load chunk c+1 -> write LDS immediately (regs transient, never live
    // across the MFMA block) -> wave (c>>1) consumes chunk c -> barrier.
    #pragma unroll 1
    for (int c = 0; c < 16; ++c) {
        const int rbase = (c & 1) * BUFS;
        const int wbase = ((c + 1) & 1) * BUFS;

        if (c < 15) {
            const int cc = c + 1;
            float4 v0, v1, v2, v3, v4;
            LOAD_SLOT(v0, 0) LOAD_SLOT(v1, 1) LOAD_SLOT(v2, 2) LOAD_SLOT(v3, 3)
            if (tid < 352) { LOAD_SLOT(v4, 4) }
            WRITE_SLOT(v0, 0) WRITE_SLOT(v1, 1) WRITE_SLOT(v2, 2) WRITE_SLOT(v3, 3)
            if (tid < 352) { WRITE_SLOT(v4, 4) }
        }
        if ((c >> 1) == wave) {
            if (c & 1) { CONSUME(2, 3) }
            else       { CONSUME(0, 1) }
        }
        __syncthreads();
    }

    // ---------------- scores: SCB[t+1][c] = sc3[t][c]; c=0..13 from acc[i][3], c=14 via shfl ----
    float* SCB = SB;                     // [514][18] floats
    #pragma unroll
    for (int i = 0; i < 4; ++i) {
        int grow = (wave * 4 + i) * 16 + kg * 4;
        #pragma unroll
        for (int r = 0; r < 4; ++r)
            if (q >= 2) SCB[(grow + r + 1) * SCSTR + (q - 2)] = acc[i][3][r];
    }
    {   // w4[t] = sum_h proj[t][40+h]*emb[4][20+h]
        float ew = 0.f;
        if (q >= 8) ew = embG[132 + q];          // h = q-8 -> embG[140+h]
        else if (q < 2) ew = embG[148 + q];      // h = 8+q
        #pragma unroll
        for (int i = 0; i < 4; ++i) {
            int grow = (wave * 4 + i) * 16 + kg * 4;
            #pragma unroll
            for (int r = 0; r < 4; ++r) {
                float p = (q >= 8) ? acc[i][2][r] * ew : ((q < 2) ? acc[i][3][r] * ew : 0.f);
                p += __shfl_xor(p, 1); p += __shfl_xor(p, 2);
                p += __shfl_xor(p, 4); p += __shfl_xor(p, 8);
                if (q == 0) SCB[(grow + r + 1) * SCSTR + 14] = p;
            }
        }
    }
    __syncthreads();
    if (tid < SCSTR)                       SCB[tid] = 0.f;                       // row 0 (t=-1)
    else if (tid >= 32 && tid < 32 + SCSTR) SCB[501 * SCSTR + (tid - 32)] = 0.f; // row 501
    __syncthreads();

    float sc[NASP];
    #pragma unroll
    for (int a = 0; a < NASP; ++a)
        sc[a] = active ? (SCB[s * SCSTR + a] + SCB[(s + 1) * SCSTR + 5 + a]
                          + SCB[(s + 2) * SCSTR + 10 + a])
                       : -1e30f;

    // ---------------- softmax ----------------
    float* red = SB + RED_OFF;
    float m[NASP];
    #pragma unroll
    for (int a = 0; a < NASP; ++a) {
        float x = sc[a];
        #pragma unroll
        for (int off = 32; off > 0; off >>= 1) x = fmaxf(x, __shfl_xor(x, off));
        if (lane == 0) red[wave * NASP + a] = x;
    }
    __syncthreads();
    #pragma unroll
    for (int a = 0; a < NASP; ++a) {
        float mm = red[a];
        #pragma unroll
        for (int w2 = 1; w2 < 8; ++w2) mm = fmaxf(mm, red[w2 * NASP + a]);
        m[a] = mm;
    }
    __syncthreads();
    float p[NASP];
    #pragma unroll
    for (int a = 0; a < NASP; ++a) {
        float x = active ? __expf(sc[a] - m[a]) : 0.f;
        p[a] = x;
        float t = x;
        #pragma unroll
        for (int off = 32; off > 0; off >>= 1) t += __shfl_xor(t, off);
        if (lane == 0) red[wave * NASP + a] = t;
    }
    __syncthreads();
    float attnv[NASP];
    #pragma unroll
    for (int a = 0; a < NASP; ++a) {
        float ssum = 0.f;
        #pragma unroll
        for (int w2 = 0; w2 < 8; ++w2) ssum += red[w2 * NASP + a];
        attnv[a] = p[a] / ssum;
    }
    if (active) {
        #pragma unroll
        for (int a = 0; a < NASP; ++a)
            out[((size_t)b * NASP + a) * SEQ + s] = attnv[a];
    }

    // ---------------- pooling via MFMA: rep[j][a] = sum_s proj[s][j]*attn[a][s] --------
    short* attnA = SBs;
    #pragma unroll
    for (int a = 0; a < NASP; ++a)
        attnA[a * ATTN_STR + s] = f2bf_rne(attnv[a]);   // s>=500 writes zeros
    __syncthreads();

    f32x4 accP[4];
    #pragma unroll
    for (int nt = 0; nt < 4; ++nt) accP[nt] = (f32x4){0.f, 0.f, 0.f, 0.f};

    #pragma unroll
    for (int f2 = 0; f2 < 2; ++f2) {
        const int i0 = f2 * 2, i1 = i0 + 1;
        const int base0 = (wave * 4 + i0) * 16 + kg * 4;
        const int base1 = (wave * 4 + i1) * 16 + kg * 4;
        short4 blo = *reinterpret_cast<const short4*>(attnA + q * ATTN_STR + base0);
        short4 bhi = *reinterpret_cast<const short4*>(attnA + q * ATTN_STR + base1);
        frag_cast b2;
        b2.s[0] = blo.x; b2.s[1] = blo.y; b2.s[2] = blo.z; b2.s[3] = blo.w;
        b2.s[4] = bhi.x; b2.s[5] = bhi.y; b2.s[6] = bhi.z; b2.s[7] = bhi.w;
        #pragma unroll
        for (int nt = 0; nt < 4; ++nt) {
            frag_cast a2;                // A-operand: projT with the same k-row permutation
            #pragma unroll
            for (int jj = 0; jj < 4; ++jj) {
                a2.b[jj]     = (__bf16)acc[i0][nt][jj];
                a2.b[4 + jj] = (__bf16)acc[i1][nt][jj];
            }
            accP[nt] = __builtin_amdgcn_mfma_f32_16x16x32_bf16(a2.b, b2.b, accP[nt], 0, 0, 0);
        }
    }
    float* PART = SB + PART_OFF;
    if (q < 5) {
        #pragma unroll
        for (int nt = 0; nt < 4; ++nt)
            #pragma unroll
            for (int r = 0; r < 4; ++r)
                PART[((wave * 4 + nt) * 16 + kg * 4 + r) * 6 + q] = accP[nt][r];
    }
    __syncthreads();
    if (tid < 50) {                      // j = proj column = tid; aspect = tid/10
        const int a = tid / 10;
        const int nt = tid >> 4, jl = tid & 15;
        float t = 0.f;
        #pragma unroll
        for (int w2 = 0; w2 < 8; ++w2)
            t += PART[((w2 * 4 + nt) * 16 + jl) * 6 + a];
        out[(size_t)B * NASP * SEQ + (size_t)b * 50 + tid] = t;
    }
}

extern "C" void kernel_launch(void* const* d_in, const int* in_sizes, int n_in,
                              void* d_out, int out_size, void* d_ws, size_t ws_size,
                              hipStream_t stream) {
    const float* doc = (const float*)d_in[0];
    const float* Wg  = (const float*)d_in[1];
    const float* emb = (const float*)d_in[2];
    float* out = (float*)d_out;
    short* Bf  = (short*)d_ws;                 // 40 KB scratch
    const int B = in_sizes[0] / (SEQ * EMB);   // 1024

    build_bfrag<<<dim3((BF_ELEMS + 255) / 256), dim3(256), 0, stream>>>(Wg, emb, Bf);
    arl_mfma<<<dim3(B), dim3(THREADS), 0, stream>>>(doc, Bf, emb, out, B);
}

// Round 19
// 147.363 us; speedup vs baseline: 1.9676x; 1.9676x over previous
//
#include <hip/hip_runtime.h>
#include <hip/hip_bf16.h>

#define NASP 5
#define H1 10
#define SEQ 500
#define EMB 300
#define THREADS 512
#define NKS 10                        // ceil(300/32) k-steps
#define BF_ELEMS (NKS * 4 * 64 * 8)   // 20480 bf16 = 40 KB
#define SCSTR 18                      // score buffer row stride (floats)
#define ATTN_STR 520                  // attn LDS row stride (shorts)
#define RED_OFF 9260                  // red[] offset (floats)
#define PART_OFF 1536                 // pooling partial buffer offset (floats), [32][16][6]

typedef float  f32x4  __attribute__((ext_vector_type(4)));
typedef __bf16 bf16x8 __attribute__((ext_vector_type(8)));
typedef short  s16x8  __attribute__((ext_vector_type(8)));
union frag_cast { s16x8 s; bf16x8 b; };

__device__ __host__ inline short f2bf_rne(float x) {
    unsigned u = __builtin_bit_cast(unsigned, x);
    u = u + 0x7FFF + ((u >> 16) & 1);
    return (short)(u >> 16);
}

// ---- prep: B-fragments Bf[ks][nt][lane][8] (bf16) ----
// nt<3 : proj cols 0..47; nt==3: q<2 -> cols 48,49 ; q>=2 -> F col c=q-2 (c=slot*5+a)
__global__ void build_bfrag(const float* __restrict__ Wg, const float* __restrict__ embG,
                            short* __restrict__ Bf) {
    int i = blockIdx.x * blockDim.x + threadIdx.x;
    if (i >= BF_ELEMS) return;
    int j    = i & 7;
    int lane = (i >> 3) & 63;
    int nt   = (i >> 9) & 3;
    int ks   = i >> 11;
    int k    = ks * 32 + (lane >> 4) * 8 + j;
    int q    = lane & 15;
    float v = 0.f;
    if (k < EMB) {
        if (nt < 3) {
            int col = nt * 16 + q;
            int a = col / 10, h = col - 10 * a;
            v = Wg[a * 3000 + k * 10 + h];
        } else if (q < 2) {
            v = Wg[4 * 3000 + k * 10 + 8 + q];
        } else {
            int c = q - 2;
            int slot = c / 5, a = c - 5 * slot;
            float sacc = 0.f;
            #pragma unroll
            for (int h = 0; h < 10; ++h)
                sacc += Wg[a * 3000 + k * 10 + h] * embG[a * 30 + slot * 10 + h];
            v = sacc;
        }
    }
    Bf[i] = f2bf_rne(v);
}

__device__ inline bf16x8 cvt8(float4 a0, float4 a1) {
    bf16x8 r;
    r[0] = (__bf16)a0.x; r[1] = (__bf16)a0.y; r[2] = (__bf16)a0.z; r[3] = (__bf16)a0.w;
    r[4] = (__bf16)a1.x; r[5] = (__bf16)a1.y; r[6] = (__bf16)a1.z; r[7] = (__bf16)a1.w;
    return r;
}

__global__ __launch_bounds__(THREADS, 4)
void arl_mfma(const float* __restrict__ doc,
              const short* __restrict__ Bf,
              const float* __restrict__ embG,
              float* __restrict__ out,
              int B) {
    __shared__ float SB[10240];          // 40 KB: B-frags / score-buf / attn+partials overlay

    const int tid  = threadIdx.x;
    const int b    = blockIdx.x;
    const int lane = tid & 63;
    const int wave = tid >> 6;
    const int q    = lane & 15;
    const int kg   = lane >> 4;
    const int s    = tid;
    const bool active = (s < SEQ);

    const float* docB = doc + (size_t)b * (SEQ * EMB);
    short* SBs = reinterpret_cast<short*>(SB);

    // ---- stage B-fragments into LDS: 20480 shorts = 2560 float4 ----
    {
        const float4* bsrc = reinterpret_cast<const float4*>(Bf);
        float4* bdst = reinterpret_cast<float4*>(SB);
        #pragma unroll
        for (int i = 0; i < 5; ++i)
            bdst[tid + i * THREADS] = bsrc[tid + i * THREADS];
    }

    const float* rowp[4];
    #pragma unroll
    for (int i = 0; i < 4; ++i) {
        int row = (wave * 4 + i) * 16 + q;
        row = row < SEQ ? row : SEQ - 1;
        rowp[i] = docB + (size_t)row * EMB + kg * 8;
    }

    f32x4 acc[4][4];
    #pragma unroll
    for (int i = 0; i < 4; ++i)
        #pragma unroll
        for (int nt = 0; nt < 4; ++nt)
            acc[i][nt] = (f32x4){0.f, 0.f, 0.f, 0.f};

    __syncthreads();                     // B staged

    // ---------------- phase 1: i-OUTER / ks-inner (DRAM page locality) ----------------
    // Per row-group i the wave reads its 16 rows' 10 x 128 B chunks in consecutive
    // iterations -> each DRAM page's accesses cluster in time (~1 activation/row vs ~10
    // in the ks-outer order). 1-deep rotation via plain scalars (no arrays: rule #20).
    #pragma unroll
    for (int i = 0; i < 4; ++i) {
        const float* rp = rowp[i];
        float4 ca = *reinterpret_cast<const float4*>(rp);
        float4 cb = *reinterpret_cast<const float4*>(rp + 4);

        #pragma unroll 1
        for (int ks = 0; ks < 9; ++ks) {
            // load next chunk (ks+1); ks==8 stages the masked tail for ks=9
            float4 na, nb;
            if (ks < 8) {
                const int ko2 = (ks + 1) * 32;
                na = *reinterpret_cast<const float4*>(rp + ko2);
                nb = *reinterpret_cast<const float4*>(rp + ko2 + 4);
            } else {
                na = (float4){0.f, 0.f, 0.f, 0.f};
                nb = (float4){0.f, 0.f, 0.f, 0.f};
                if (kg == 0) { na = *reinterpret_cast<const float4*>(rp + 288);
                               nb = *reinterpret_cast<const float4*>(rp + 292); }
                else if (kg == 1) { na = *reinterpret_cast<const float4*>(rp + 288); }
            }

            frag_cast bfr0, bfr1, bfr2, bfr3;
            bfr0.s = *reinterpret_cast<const s16x8*>(SBs + ((size_t)(ks * 4 + 0) * 64 + lane) * 8);
            bfr1.s = *reinterpret_cast<const s16x8*>(SBs + ((size_t)(ks * 4 + 1) * 64 + lane) * 8);
            bfr2.s = *reinterpret_cast<const s16x8*>(SBs + ((size_t)(ks * 4 + 2) * 64 + lane) * 8);
            bfr3.s = *reinterpret_cast<const s16x8*>(SBs + ((size_t)(ks * 4 + 3) * 64 + lane) * 8);

            bf16x8 af = cvt8(ca, cb);
            acc[i][0] = __builtin_amdgcn_mfma_f32_16x16x32_bf16(af, bfr0.b, acc[i][0], 0, 0, 0);
            acc[i][1] = __builtin_amdgcn_mfma_f32_16x16x32_bf16(af, bfr1.b, acc[i][1], 0, 0, 0);
            acc[i][2] = __builtin_amdgcn_mfma_f32_16x16x32_bf16(af, bfr2.b, acc[i][2], 0, 0, 0);
            acc[i][3] = __builtin_amdgcn_mfma_f32_16x16x32_bf16(af, bfr3.b, acc[i][3], 0, 0, 0);

            ca = na; cb = nb;
        }
        {   // ks = 9: consume the tail staged during ks=8
            frag_cast bfr0, bfr1, bfr2, bfr3;
            bfr0.s = *reinterpret_cast<const s16x8*>(SBs + ((size_t)(9 * 4 + 0) * 64 + lane) * 8);
            bfr1.s = *reinterpret_cast<const s16x8*>(SBs + ((size_t)(9 * 4 + 1) * 64 + lane) * 8);
            bfr2.s = *reinterpret_cast<const s16x8*>(SBs + ((size_t)(9 * 4 + 2) * 64 + lane) * 8);
            bfr3.s = *reinterpret_cast<const s16x8*>(SBs + ((size_t)(9 * 4 + 3) * 64 + lane) * 8);
            bf16x8 af = cvt8(ca, cb);
            acc[i][0] = __builtin_amdgcn_mfma_f32_16x16x32_bf16(af, bfr0.b, acc[i][0], 0, 0, 0);
            acc[i][1] = __builtin_amdgcn_mfma_f32_16x16x32_bf16(af, bfr1.b, acc[i][1], 0, 0, 0);
            acc[i][2] = __builtin_amdgcn_mfma_f32_16x16x32_bf16(af, bfr2.b, acc[i][2], 0, 0, 0);
            acc[i][3] = __builtin_amdgcn_mfma_f32_16x16x32_bf16(af, bfr3.b, acc[i][3], 0, 0, 0);
        }
    }
    __syncthreads();                     // B-frag LDS dead -> score buffer may overwrite

    // ---------------- scores: SCB[t+1][c] = sc3[t][c]; c=0..13 from acc[i][3], c=14 via shfl ----
    float* SCB = SB;                     // [514][18] floats
    #pragma unroll
    for (int i = 0; i < 4; ++i) {
        int grow = (wave * 4 + i) * 16 + kg * 4;
        #pragma unroll
        for (int r = 0; r < 4; ++r)
            if (q >= 2) SCB[(grow + r + 1) * SCSTR + (q - 2)] = acc[i][3][r];
    }
    {   // w4[t] = sum_h proj[t][40+h]*emb[4][20+h]
        float ew = 0.f;
        if (q >= 8) ew = embG[132 + q];          // h = q-8 -> embG[140+h]
        else if (q < 2) ew = embG[148 + q];      // h = 8+q
        #pragma unroll
        for (int i = 0; i < 4; ++i) {
            int grow = (wave * 4 + i) * 16 + kg * 4;
            #pragma unroll
            for (int r = 0; r < 4; ++r) {
                float p = (q >= 8) ? acc[i][2][r] * ew : ((q < 2) ? acc[i][3][r] * ew : 0.f);
                p += __shfl_xor(p, 1); p += __shfl_xor(p, 2);
                p += __shfl_xor(p, 4); p += __shfl_xor(p, 8);
                if (q == 0) SCB[(grow + r + 1) * SCSTR + 14] = p;
            }
        }
    }
    __syncthreads();
    if (tid < SCSTR)                       SCB[tid] = 0.f;                       // row 0 (t=-1)
    else if (tid >= 32 && tid < 32 + SCSTR) SCB[501 * SCSTR + (tid - 32)] = 0.f; // row 501
    __syncthreads();

    float sc[NASP];
    #pragma unroll
    for (int a = 0; a < NASP; ++a)
        sc[a] = active ? (SCB[s * SCSTR + a] + SCB[(s + 1) * SCSTR + 5 + a]
                          + SCB[(s + 2) * SCSTR + 10 + a])
                       : -1e30f;

    // ---------------- softmax ----------------
    float* red = SB + RED_OFF;
    float m[NASP];
    #pragma unroll
    for (int a = 0; a < NASP; ++a) {
        float x = sc[a];
        #pragma unroll
        for (int off = 32; off > 0; off >>= 1) x = fmaxf(x, __shfl_xor(x, off));
        if (lane == 0) red[wave * NASP + a] = x;
    }
    __syncthreads();
    #pragma unroll
    for (int a = 0; a < NASP; ++a) {
        float mm = red[a];
        #pragma unroll
        for (int w2 = 1; w2 < 8; ++w2) mm = fmaxf(mm, red[w2 * NASP + a]);
        m[a] = mm;
    }
    __syncthreads();
    float p[NASP];
    #pragma unroll
    for (int a = 0; a < NASP; ++a) {
        float x = active ? __expf(sc[a] - m[a]) : 0.f;
        p[a] = x;
        float t = x;
        #pragma unroll
        for (int off = 32; off > 0; off >>= 1) t += __shfl_xor(t, off);
        if (lane == 0) red[wave * NASP + a] = t;
    }
    __syncthreads();
    float attnv[NASP];
    #pragma unroll
    for (int a = 0; a < NASP; ++a) {
        float ssum = 0.f;
        #pragma unroll
        for (int w2 = 0; w2 < 8; ++w2) ssum += red[w2 * NASP + a];
        attnv[a] = p[a] / ssum;
    }
    if (active) {
        #pragma unroll
        for (int a = 0; a < NASP; ++a)
            out[((size_t)b * NASP + a) * SEQ + s] = attnv[a];
    }

    // ---------------- pooling via MFMA: rep[j][a] = sum_s proj[s][j]*attn[a][s] --------
    short* attnA = SBs;
    #pragma unroll
    for (int a = 0; a < NASP; ++a)
        attnA[a * ATTN_STR + s] = f2bf_rne(attnv[a]);   // s>=500 writes zeros
    __syncthreads();

    f32x4 accP[4];
    #pragma unroll
    for (int nt = 0; nt < 4; ++nt) accP[nt] = (f32x4){0.f, 0.f, 0.f, 0.f};

    #pragma unroll
    for (int f2 = 0; f2 < 2; ++f2) {
        const int i0 = f2 * 2, i1 = i0 + 1;
        const int base0 = (wave * 4 + i0) * 16 + kg * 4;
        const int base1 = (wave * 4 + i1) * 16 + kg * 4;
        short4 blo = *reinterpret_cast<const short4*>(attnA + q * ATTN_STR + base0);
        short4 bhi = *reinterpret_cast<const short4*>(attnA + q * ATTN_STR + base1);
        frag_cast b2;
        b2.s[0] = blo.x; b2.s[1] = blo.y; b2.s[2] = blo.z; b2.s[3] = blo.w;
        b2.s[4] = bhi.x; b2.s[5] = bhi.y; b2.s[6] = bhi.z; b2.s[7] = bhi.w;
        #pragma unroll
        for (int nt = 0; nt < 4; ++nt) {
            frag_cast a2;                // A-operand: projT with the same k-row permutation
            #pragma unroll
            for (int jj = 0; jj < 4; ++jj) {
                a2.b[jj]     = (__bf16)acc[i0][nt][jj];
                a2.b[4 + jj] = (__bf16)acc[i1][nt][jj];
            }
            accP[nt] = __builtin_amdgcn_mfma_f32_16x16x32_bf16(a2.b, b2.b, accP[nt], 0, 0, 0);
        }
    }
    float* PART = SB + PART_OFF;
    if (q < 5) {
        #pragma unroll
        for (int nt = 0; nt < 4; ++nt)
            #pragma unroll
            for (int r = 0; r < 4; ++r)
                PART[((wave * 4 + nt) * 16 + kg * 4 + r) * 6 + q] = accP[nt][r];
    }
    __syncthreads();
    if (tid < 50) {                      // j = proj column = tid; aspect = tid/10
        const int a = tid / 10;
        const int nt = tid >> 4, jl = tid & 15;
        float t = 0.f;
        #pragma unroll
        for (int w2 = 0; w2 < 8; ++w2)
            t += PART[((w2 * 4 + nt) * 16 + jl) * 6 + a];
        out[(size_t)B * NASP * SEQ + (size_t)b * 50 + tid] = t;
    }
}

extern "C" void kernel_launch(void* const* d_in, const int* in_sizes, int n_in,
                              void* d_out, int out_size, void* d_ws, size_t ws_size,
                              hipStream_t stream) {
    const float* doc = (const float*)d_in[0];
    const float* Wg  = (const float*)d_in[1];
    const float* emb = (const float*)d_in[2];
    float* out = (float*)d_out;
    short* Bf  = (short*)d_ws;                 // 40 KB scratch
    const int B = in_sizes[0] / (SEQ * EMB);   // 1024

    build_bfrag<<<dim3((BF_ELEMS + 255) / 256), dim3(256), 0, stream>>>(Wg, emb, Bf);
    arl_mfma<<<dim3(B), dim3(THREADS), 0, stream>>>(doc, Bf, emb, out, B);
}

// Round 20
// 143.978 us; speedup vs baseline: 2.0139x; 1.0235x over previous
//
#include <hip/hip_runtime.h>
#include <hip/hip_bf16.h>

#define NASP 5
#define H1 10
#define SEQ 500
#define EMB 300
#define THREADS 512
#define NKS 10                        // ceil(300/32) k-steps
#define BF_ELEMS (NKS * 4 * 64 * 8)   // 20480 bf16 = 40 KB
#define SCSTR 18                      // score buffer row stride (floats)
#define ATTN_STR 520                  // attn LDS row stride (shorts)
#define RED_OFF 9260                  // red[] offset (floats)
#define PART_OFF 1536                 // pooling partial buffer offset (floats), [32][16][6]

typedef float  f32x4  __attribute__((ext_vector_type(4)));
typedef __bf16 bf16x8 __attribute__((ext_vector_type(8)));
typedef short  s16x8  __attribute__((ext_vector_type(8)));
union frag_cast { s16x8 s; bf16x8 b; };

__device__ __host__ inline short f2bf_rne(float x) {
    unsigned u = __builtin_bit_cast(unsigned, x);
    u = u + 0x7FFF + ((u >> 16) & 1);
    return (short)(u >> 16);
}

// ---- prep: B-fragments Bf[ks][nt][lane][8] (bf16) ----
// nt<3 : proj cols 0..47; nt==3: q<2 -> cols 48,49 ; q>=2 -> F col c=q-2 (c=slot*5+a)
__global__ void build_bfrag(const float* __restrict__ Wg, const float* __restrict__ embG,
                            short* __restrict__ Bf) {
    int i = blockIdx.x * blockDim.x + threadIdx.x;
    if (i >= BF_ELEMS) return;
    int j    = i & 7;
    int lane = (i >> 3) & 63;
    int nt   = (i >> 9) & 3;
    int ks   = i >> 11;
    int k    = ks * 32 + (lane >> 4) * 8 + j;
    int q    = lane & 15;
    float v = 0.f;
    if (k < EMB) {
        if (nt < 3) {
            int col = nt * 16 + q;
            int a = col / 10, h = col - 10 * a;
            v = Wg[a * 3000 + k * 10 + h];
        } else if (q < 2) {
            v = Wg[4 * 3000 + k * 10 + 8 + q];
        } else {
            int c = q - 2;
            int slot = c / 5, a = c - 5 * slot;
            float sacc = 0.f;
            #pragma unroll
            for (int h = 0; h < 10; ++h)
                sacc += Wg[a * 3000 + k * 10 + h] * embG[a * 30 + slot * 10 + h];
            v = sacc;
        }
    }
    Bf[i] = f2bf_rne(v);
}

__device__ inline bf16x8 cvt8(float4 a0, float4 a1) {
    bf16x8 r;
    r[0] = (__bf16)a0.x; r[1] = (__bf16)a0.y; r[2] = (__bf16)a0.z; r[3] = (__bf16)a0.w;
    r[4] = (__bf16)a1.x; r[5] = (__bf16)a1.y; r[6] = (__bf16)a1.z; r[7] = (__bf16)a1.w;
    return r;
}

__global__ __launch_bounds__(THREADS, 4)
void arl_mfma(const float* __restrict__ doc,
              const short* __restrict__ Bf,
              const float* __restrict__ embG,
              float* __restrict__ out,
              int B) {
    __shared__ float SB[10240];          // 40 KB: B-frags / score-buf / attn+partials overlay

    const int tid  = threadIdx.x;
    const int b    = blockIdx.x;
    const int lane = tid & 63;
    const int wave = tid >> 6;
    const int q    = lane & 15;
    const int kg   = lane >> 4;
    const int s    = tid;
    const bool active = (s < SEQ);

    const float* docB = doc + (size_t)b * (SEQ * EMB);
    short* SBs = reinterpret_cast<short*>(SB);

    // ---- stage B-fragments into LDS: 20480 shorts = 2560 float4 ----
    {
        const float4* bsrc = reinterpret_cast<const float4*>(Bf);
        float4* bdst = reinterpret_cast<float4*>(SB);
        #pragma unroll
        for (int i = 0; i < 5; ++i)
            bdst[tid + i * THREADS] = bsrc[tid + i * THREADS];
    }

    const float* rowp[4];
    #pragma unroll
    for (int i = 0; i < 4; ++i) {
        int row = (wave * 4 + i) * 16 + q;
        row = row < SEQ ? row : SEQ - 1;
        rowp[i] = docB + (size_t)row * EMB + kg * 8;
    }

    f32x4 acc[4][4];
    #pragma unroll
    for (int i = 0; i < 4; ++i)
        #pragma unroll
        for (int nt = 0; nt < 4; ++nt)
            acc[i][nt] = (f32x4){0.f, 0.f, 0.f, 0.f};

    __syncthreads();                     // B staged

    // ---------------- phase 1: i-OUTER / ks-inner, 2-deep load rotation ----------------
    // Page locality (r19, +19%) kept; rotation deepened to 2 so each load has ~2
    // iterations of cover (~400 cyc/wave, ~1600 with 4-wave SIMD rotation > ~900 HBM).
    // Plain named float4 pairs only (rule #20). Accumulation order unchanged.
    #pragma unroll
    for (int i = 0; i < 4; ++i) {
        const float* rp = rowp[i];
        float4 c0a = *reinterpret_cast<const float4*>(rp);
        float4 c0b = *reinterpret_cast<const float4*>(rp + 4);
        float4 c1a = *reinterpret_cast<const float4*>(rp + 32);
        float4 c1b = *reinterpret_cast<const float4*>(rp + 36);

        #pragma unroll 1
        for (int ks = 0; ks < NKS; ++ks) {
            // issue load for chunk ks+2 (2 ahead); ks==7 stages the masked tail (chunk 9)
            float4 ta = (float4){0.f, 0.f, 0.f, 0.f};
            float4 tb = (float4){0.f, 0.f, 0.f, 0.f};
            if (ks < 7) {
                const int ko2 = (ks + 2) * 32;
                ta = *reinterpret_cast<const float4*>(rp + ko2);
                tb = *reinterpret_cast<const float4*>(rp + ko2 + 4);
            } else if (ks == 7) {
                if (kg == 0) { ta = *reinterpret_cast<const float4*>(rp + 288);
                               tb = *reinterpret_cast<const float4*>(rp + 292); }
                else if (kg == 1) { ta = *reinterpret_cast<const float4*>(rp + 288); }
            }

            frag_cast bfr0, bfr1, bfr2, bfr3;
            bfr0.s = *reinterpret_cast<const s16x8*>(SBs + ((size_t)(ks * 4 + 0) * 64 + lane) * 8);
            bfr1.s = *reinterpret_cast<const s16x8*>(SBs + ((size_t)(ks * 4 + 1) * 64 + lane) * 8);
            bfr2.s = *reinterpret_cast<const s16x8*>(SBs + ((size_t)(ks * 4 + 2) * 64 + lane) * 8);
            bfr3.s = *reinterpret_cast<const s16x8*>(SBs + ((size_t)(ks * 4 + 3) * 64 + lane) * 8);

            bf16x8 af = cvt8(c0a, c0b);
            acc[i][0] = __builtin_amdgcn_mfma_f32_16x16x32_bf16(af, bfr0.b, acc[i][0], 0, 0, 0);
            acc[i][1] = __builtin_amdgcn_mfma_f32_16x16x32_bf16(af, bfr1.b, acc[i][1], 0, 0, 0);
            acc[i][2] = __builtin_amdgcn_mfma_f32_16x16x32_bf16(af, bfr2.b, acc[i][2], 0, 0, 0);
            acc[i][3] = __builtin_amdgcn_mfma_f32_16x16x32_bf16(af, bfr3.b, acc[i][3], 0, 0, 0);

            c0a = c1a; c0b = c1b; c1a = ta; c1b = tb;
        }
    }
    __syncthreads();                     // B-frag LDS dead -> score buffer may overwrite

    // ---------------- scores: SCB[t+1][c] = sc3[t][c]; c=0..13 from acc[i][3], c=14 via shfl ----
    float* SCB = SB;                     // [514][18] floats
    #pragma unroll
    for (int i = 0; i < 4; ++i) {
        int grow = (wave * 4 + i) * 16 + kg * 4;
        #pragma unroll
        for (int r = 0; r < 4; ++r)
            if (q >= 2) SCB[(grow + r + 1) * SCSTR + (q - 2)] = acc[i][3][r];
    }
    {   // w4[t] = sum_h proj[t][40+h]*emb[4][20+h]
        float ew = 0.f;
        if (q >= 8) ew = embG[132 + q];          // h = q-8 -> embG[140+h]
        else if (q < 2) ew = embG[148 + q];      // h = 8+q
        #pragma unroll
        for (int i = 0; i < 4; ++i) {
            int grow = (wave * 4 + i) * 16 + kg * 4;
            #pragma unroll
            for (int r = 0; r < 4; ++r) {
                float p = (q >= 8) ? acc[i][2][r] * ew : ((q < 2) ? acc[i][3][r] * ew : 0.f);
                p += __shfl_xor(p, 1); p += __shfl_xor(p, 2);
                p += __shfl_xor(p, 4); p += __shfl_xor(p, 8);
                if (q == 0) SCB[(grow + r + 1) * SCSTR + 14] = p;
            }
        }
    }
    __syncthreads();
    if (tid < SCSTR)                       SCB[tid] = 0.f;                       // row 0 (t=-1)
    else if (tid >= 32 && tid < 32 + SCSTR) SCB[501 * SCSTR + (tid - 32)] = 0.f; // row 501
    __syncthreads();

    float sc[NASP];
    #pragma unroll
    for (int a = 0; a < NASP; ++a)
        sc[a] = active ? (SCB[s * SCSTR + a] + SCB[(s + 1) * SCSTR + 5 + a]
                          + SCB[(s + 2) * SCSTR + 10 + a])
                       : -1e30f;

    // ---------------- softmax ----------------
    float* red = SB + RED_OFF;
    float m[NASP];
    #pragma unroll
    for (int a = 0; a < NASP; ++a) {
        float x = sc[a];
        #pragma unroll
        for (int off = 32; off > 0; off >>= 1) x = fmaxf(x, __shfl_xor(x, off));
        if (lane == 0) red[wave * NASP + a] = x;
    }
    __syncthreads();
    #pragma unroll
    for (int a = 0; a < NASP; ++a) {
        float mm = red[a];
        #pragma unroll
        for (int w2 = 1; w2 < 8; ++w2) mm = fmaxf(mm, red[w2 * NASP + a]);
        m[a] = mm;
    }
    __syncthreads();
    float p[NASP];
    #pragma unroll
    for (int a = 0; a < NASP; ++a) {
        float x = active ? __expf(sc[a] - m[a]) : 0.f;
        p[a] = x;
        float t = x;
        #pragma unroll
        for (int off = 32; off > 0; off >>= 1) t += __shfl_xor(t, off);
        if (lane == 0) red[wave * NASP + a] = t;
    }
    __syncthreads();
    float attnv[NASP];
    #pragma unroll
    for (int a = 0; a < NASP; ++a) {
        float ssum = 0.f;
        #pragma unroll
        for (int w2 = 0; w2 < 8; ++w2) ssum += red[w2 * NASP + a];
        attnv[a] = p[a] / ssum;
    }
    if (active) {
        #pragma unroll
        for (int a = 0; a < NASP; ++a)
            out[((size_t)b * NASP + a) * SEQ + s] = attnv[a];
    }

    // ---------------- pooling via MFMA: rep[j][a] = sum_s proj[s][j]*attn[a][s] --------
    short* attnA = SBs;
    #pragma unroll
    for (int a = 0; a < NASP; ++a)
        attnA[a * ATTN_STR + s] = f2bf_rne(attnv[a]);   // s>=500 writes zeros
    __syncthreads();

    f32x4 accP[4];
    #pragma unroll
    for (int nt = 0; nt < 4; ++nt) accP[nt] = (f32x4){0.f, 0.f, 0.f, 0.f};

    #pragma unroll
    for (int f2 = 0; f2 < 2; ++f2) {
        const int i0 = f2 * 2, i1 = i0 + 1;
        const int base0 = (wave * 4 + i0) * 16 + kg * 4;
        const int base1 = (wave * 4 + i1) * 16 + kg * 4;
        short4 blo = *reinterpret_cast<const short4*>(attnA + q * ATTN_STR + base0);
        short4 bhi = *reinterpret_cast<const short4*>(attnA + q * ATTN_STR + base1);
        frag_cast b2;
        b2.s[0] = blo.x; b2.s[1] = blo.y; b2.s[2] = blo.z; b2.s[3] = blo.w;
        b2.s[4] = bhi.x; b2.s[5] = bhi.y; b2.s[6] = bhi.z; b2.s[7] = bhi.w;
        #pragma unroll
        for (int nt = 0; nt < 4; ++nt) {
            frag_cast a2;                // A-operand: projT with the same k-row permutation
            #pragma unroll
            for (int jj = 0; jj < 4; ++jj) {
                a2.b[jj]     = (__bf16)acc[i0][nt][jj];
                a2.b[4 + jj] = (__bf16)acc[i1][nt][jj];
            }
            accP[nt] = __builtin_amdgcn_mfma_f32_16x16x32_bf16(a2.b, b2.b, accP[nt], 0, 0, 0);
        }
    }
    float* PART = SB + PART_OFF;
    if (q < 5) {
        #pragma unroll
        for (int nt = 0; nt < 4; ++nt)
            #pragma unroll
            for (int r = 0; r < 4; ++r)
                PART[((wave * 4 + nt) * 16 + kg * 4 + r) * 6 + q] = accP[nt][r];
    }
    __syncthreads();
    if (tid < 50) {                      // j = proj column = tid; aspect = tid/10
        const int a = tid / 10;
        const int nt = tid >> 4, jl = tid & 15;
        float t = 0.f;
        #pragma unroll
        for (int w2 = 0; w2 < 8; ++w2)
            t += PART[((w2 * 4 + nt) * 16 + jl) * 6 + a];
        out[(size_t)B * NASP * SEQ + (size_t)b * 50 + tid] = t;
    }
}

extern "C" void kernel_launch(void* const* d_in, const int* in_sizes, int n_in,
                              void* d_out, int out_size, void* d_ws, size_t ws_size,
                              hipStream_t stream) {
    const float* doc = (const float*)d_in[0];
    const float* Wg  = (const float*)d_in[1];
    const float* emb = (const float*)d_in[2];
    float* out = (float*)d_out;
    short* Bf  = (short*)d_ws;                 // 40 KB scratch
    const int B = in_sizes[0] / (SEQ * EMB);   // 1024

    build_bfrag<<<dim3((BF_ELEMS + 255) / 256), dim3(256), 0, stream>>>(Wg, emb, Bf);
    arl_mfma<<<dim3(B), dim3(THREADS), 0, stream>>>(doc, Bf, emb, out, B);
}